// Round 7
// baseline (151.431 us; speedup 1.0000x reference)
//
#include <hip/hip_runtime.h>

typedef __bf16 bf16x8 __attribute__((ext_vector_type(8)));
typedef float f32x4 __attribute__((ext_vector_type(4)));
typedef unsigned int u32x2 __attribute__((ext_vector_type(2)));
typedef unsigned short u16;
typedef unsigned int u32;

__device__ __forceinline__ float bf2f(u16 v) {
    union { unsigned u; float f; } x; x.u = ((unsigned)v) << 16; return x.f;
}
__device__ __forceinline__ u16 f2bf(float f) {
    union { float f; unsigned u; } x; x.f = f;
    unsigned r = x.u + 0x7fffu + ((x.u >> 16) & 1u);
    return (u16)(r >> 16);
}

// Runtime dtype probe (HW-verified r4): f32 buffer -> low u16 of each word is
// mantissa bits -> bf16-exponent ~uniform (~44% >= 0x90); bf16 buffer -> 0 hits.
__device__ __forceinline__ bool probe_is_f32(const void* xp) {
    const unsigned* p = (const unsigned*)xp;
    int hits = 0;
#pragma unroll
    for (int i = 0; i < 32; i++) {
        const unsigned e = (p[i] >> 7) & 0xffu;
        hits += (e >= 0x90u) ? 1 : 0;
    }
    return hits > 3;
}

__device__ __forceinline__ float ld1(const void* p, size_t i, bool isf32) {
    return isf32 ? ((const float*)p)[i] : bf2f(((const u16*)p)[i]);
}

// Async global->LDS DMA, 16B/lane; LDS dest = wave-uniform base + lane*16.
__device__ __forceinline__ void gl2lds16(const void* g, void* l) {
    __builtin_amdgcn_global_load_lds(
        (const __attribute__((address_space(1))) u32*)g,
        (__attribute__((address_space(3))) u32*)l, 16, 0, 0);
}

// Input normalization, r17: WEIGHTS ONLY (x-pass deleted -- the QKV GEMM
// now stages raw x with on-the-fly conversion; in bf16-input mode the x
// copy was pure waste). rpb -> f32 * log2(e).
__global__ __launch_bounds__(256)
void convert_inputs(const void* __restrict__ x, const void* __restrict__ qw,
                    const void* __restrict__ qb, const void* __restrict__ pw,
                    const void* __restrict__ pb, const void* __restrict__ rp,
                    u16* __restrict__ qwbf, u16* __restrict__ qbbf,
                    u16* __restrict__ pwbf, u16* __restrict__ pbbf,
                    float* __restrict__ rpl2e)
{
    const bool isf32 = probe_is_f32(x);
    const int gid = blockIdx.x * 256 + threadIdx.x;
    const int gsz = gridDim.x * 256;

    struct Seg { const void* s; u16* d; int n; };
    const Seg segs[4] = {{qw, qwbf, 786432}, {pw, pwbf, 262144},
                         {qb, qbbf, 1536}, {pb, pbbf, 512}};
    for (int t = 0; t < 4; t++) {
        const int n4 = segs[t].n >> 2;
        if (isf32) {
            const f32x4* s = (const f32x4*)segs[t].s;
            for (int i = gid; i < n4; i += gsz) {
                f32x4 v = s[i];
                ushort4 o;
                o.x = f2bf(v[0]); o.y = f2bf(v[1]); o.z = f2bf(v[2]); o.w = f2bf(v[3]);
                *(ushort4*)(segs[t].d + i * 4) = o;
            }
        } else {
            const ushort4* s = (const ushort4*)segs[t].s;
            for (int i = gid; i < n4; i += gsz) *(ushort4*)(segs[t].d + i * 4) = s[i];
        }
    }
    for (int i = gid; i < 63504; i += gsz)
        rpl2e[i] = ld1(rp, i, isf32) * 1.4426950408889634f;
}

// GEMM D = A(MxK) @ W(NoutxK)^T + bias, bf16 MFMA, fp32 accum. BMx128 tile.
// MODE 0: bias[col]; dual-dtype row-major store to d_out (probe decides).
// MODE 1 (TRANSPOSED QKV): A = qkv_w (rows = channels), W-arg = RAW x (rows
//   = tokens; r17: dual-dtype staging -- f32 path reg-stages with on-the-fly
//   f2bf into the same LDS slots gl2lds16 would fill; bf16 path keeps DMA).
//   D[ch][tok]. bias[row]. which = m0>>9 block-uniform.
//   q,k,v all -> [b][h][t][c] packed ushort4 (r16).
//   r17: q output PRE-SCALED by SC = d^-0.5*log2e (folded into the bias fma,
//   zero extra rounding) so attn's softmax needs no fma before exp2.
template<int MODE, int BM>
__global__ __launch_bounds__(256, MODE == 1 ? 3 : 4)
void gemm_bt(const u16* __restrict__ A, const void* __restrict__ W,
             const u16* __restrict__ bias, void* __restrict__ out,
             u16* __restrict__ q_out, u16* __restrict__ k_out, u16* __restrict__ v_out,
             const void* __restrict__ probe, int Nout, int K)
{
    __shared__ __align__(16) u16 As[2][BM * 32];
    __shared__ __align__(16) u16 Ws[2][128 * 32];
    constexpr int RW = BM / 32;            // A-frags per wave

    const int tid  = threadIdx.x;
    const int lane = tid & 63;
    const int wave = tid >> 6;
    const int quad = lane >> 4;
    const int l16  = lane & 15;
    const int m0 = blockIdx.y * BM;
    const int n0 = blockIdx.x * 128;
    const int wm = (wave >> 1) * (BM / 2);
    const int wn = (wave & 1) * 64;

    const bool isf32 = probe_is_f32(probe);   // block-uniform
    const u16* Wb = (const u16*)W;
    const float* Wf = (const float*)W;

    f32x4 acc[RW][4] = {};

    for (int k0 = 0; k0 < K; k0 += 64) {
        __syncthreads();
        for (int u = 0; u < 2; u++) {
            {
                const u16* g = A + (size_t)(m0 + wave * 16 + (lane >> 2)) * K
                                 + k0 + u * 32 + (lane & 3) * 8;
                u16* l = As[u] + wave * 16 * 32;
                for (int p = 0; p < BM / 64; p++) gl2lds16(g + (size_t)p * 64 * K, l + p * 64 * 32);
            }
            if (MODE == 1 && isf32) {
                // reg-staged f32 -> bf16 conversion into the same LDS slots
                const float* gx = Wf + (size_t)(n0 + wave * 16 + (lane >> 2)) * K
                                  + k0 + u * 32 + (lane & 3) * 8;
                for (int p = 0; p < 2; p++) {
                    f32x4 a = *(const f32x4*)(gx + (size_t)p * 64 * K);
                    f32x4 c = *(const f32x4*)(gx + (size_t)p * 64 * K + 4);
                    ushort4 lo, hi;
                    lo.x = f2bf(a[0]); lo.y = f2bf(a[1]); lo.z = f2bf(a[2]); lo.w = f2bf(a[3]);
                    hi.x = f2bf(c[0]); hi.y = f2bf(c[1]); hi.z = f2bf(c[2]); hi.w = f2bf(c[3]);
                    u16* d = Ws[u] + wave * 16 * 32 + p * 64 * 32 + lane * 8;
                    *(ushort4*)(d) = lo;
                    *(ushort4*)(d + 4) = hi;
                }
            } else {
                const u16* g = Wb + (size_t)(n0 + wave * 16 + (lane >> 2)) * K
                                 + k0 + u * 32 + (lane & 3) * 8;
                u16* l = Ws[u] + wave * 16 * 32;
                for (int p = 0; p < 2; p++) gl2lds16(g + (size_t)p * 64 * K, l + p * 64 * 32);
            }
        }
        __syncthreads();

        for (int u = 0; u < 2; u++) {
            bf16x8 af[RW], wf[4];
            for (int i = 0; i < RW; i++)
                af[i] = *(const bf16x8*)(As[u] + (wm + i * 16 + l16) * 32 + quad * 8);
            for (int j = 0; j < 4; j++)
                wf[j] = *(const bf16x8*)(Ws[u] + (wn + j * 16 + l16) * 32 + quad * 8);
            for (int i = 0; i < RW; i++)
                for (int j = 0; j < 4; j++)
                    acc[i][j] = __builtin_amdgcn_mfma_f32_16x16x32_bf16(af[i], wf[j], acc[i][j], 0, 0, 0);
        }
    }

    // D layout per 16x16 tile: row = quad*4 + r, col = l16
    if (MODE == 0) {
        for (int j = 0; j < 4; j++) {
            const int col = n0 + wn + j * 16 + l16;
            const float bv = bf2f(bias[col]);
            for (int i = 0; i < RW; i++) {
                const int rbase = m0 + wm + i * 16 + quad * 4;
                for (int r = 0; r < 4; r++) {
                    const float val = acc[i][j][r] + bv;
                    if (isf32) ((float*)out)[(size_t)(rbase + r) * Nout + col] = val;
                    else       ((u16*)out)[(size_t)(rbase + r) * Nout + col]  = f2bf(val);
                }
            }
        }
    } else {
        const int which = m0 >> 9;       // block-uniform (m0 128-aligned)
        u16* dst = which == 0 ? q_out : (which == 1 ? k_out : v_out);
        // q pre-scale: SC folded into the bias fma (single bf16 rounding).
        const float qsc = (which == 0) ? 0.25503485724582146f : 1.0f;
        float bv[RW][4];
        for (int i = 0; i < RW; i++) {
            const int row4 = m0 + wm + i * 16 + quad * 4;
            for (int r = 0; r < 4; r++) bv[i][r] = bf2f(bias[row4 + r]) * qsc;
        }
        for (int j = 0; j < 4; j++) {
            const int tok = n0 + wn + j * 16 + l16;
            const int bi = tok >> 10, t = tok & 1023;
            for (int i = 0; i < RW; i++) {
                ushort4 pk;
                pk.x = f2bf(acc[i][j][0] * qsc + bv[i][0]);
                pk.y = f2bf(acc[i][j][1] * qsc + bv[i][1]);
                pk.z = f2bf(acc[i][j][2] * qsc + bv[i][2]);
                pk.w = f2bf(acc[i][j][3] * qsc + bv[i][3]);
                const int row4 = m0 + wm + i * 16 + quad * 4;
                const int h = (row4 >> 5) & 15;
                const int c = row4 & 31;
                *(ushort4*)(dst + ((size_t)(bi * 16 + h) * 1024 + t) * 32 + c) = pk;
            }
        }
    }
}

// Flash attention, S^T formulation, offset-free softmax, MFMA denominator,
// T12 in-register P transpose (r14), V transposed during staging (r16).
// XCD-SWIZZLED GRID (r10): grid (16,8,8) x=h,y=qt,z=b.
//
// Ledger: r11 K/V-from-global regressed (latency-bound, 4 blocks/CU cap);
// r12 setprio null; r13 bias reg-window neutral; r14 T12 permlane WIN
// (chain-shortening is the only lever that moves attn); r15 TQ=64 null;
// r16 V-transpose-in-staging neutral.
// r17 (this round): softmax FMA stage DELETED. q arrives pre-scaled by
// SC (GEMM epilogue), and the bias window enters as the QK MFMA C-operand
// (window kept as f32x4 chunks -- exactly the C layout). Per element the
// softmax is now just exp2(s4) -> cvt -> pack: -32 VALU/kt/wave and one
// fewer dependent stage on the QK->exp2->PV serial chain.
__global__ __launch_bounds__(256, 4)
void attn(const u16* __restrict__ q, const u16* __restrict__ k,
          const u16* __restrict__ v, const float* __restrict__ rpl2e,
          u16* __restrict__ o)
{
    __shared__ __align__(16) u16 Ks[2][64 * 40];
    __shared__ __align__(16) u16 Vt[2][32 * 72];
    __shared__ float biasT[63 * 37];   // [col][row], 35 rows + 2 pad

    const int tid  = threadIdx.x;
    const int lane = tid & 63;
    const int wave = tid >> 6;
    const int quad = lane >> 4;
    const int l16  = lane & 15;

    const int h  = blockIdx.x;   // 16 heads (fastest -> fixes XCD class)
    const int qt = blockIdx.y;   // 8 q-tiles of 128
    const int b  = blockIdx.z;
    const int n0 = qt * 128;
    const size_t base = ((size_t)(b * 16 + h)) * 32768;  // q,k,v all [t][c]

    // ---- prologue: bias region (transposed), kt=0 K/V, Q frags ----
    {
        const int row0 = 28 - 4 * qt;
        for (int idx = tid; idx < 2205; idx += 256) {
            const int rr = idx / 63, cc = idx % 63;
            biasT[cc * 37 + rr] =
                rpl2e[(size_t)h * 3969 + (size_t)(row0 + rr) * 63 + cc];
        }
    }
    const int vt_t = lane;        // token within kv-tile
    const int vcg  = wave;        // c-group: c = vcg*8 .. +7
    uint4 kreg = *(const uint4*)(k + base + (size_t)(tid >> 2) * 32 + (tid & 3) * 8);
    uint4 vreg = *(const uint4*)(v + base + (size_t)vt_t * 32 + vcg * 8);
    *(uint4*)(Ks[0] + (tid >> 2) * 40 + (tid & 3) * 8) = kreg;
    {
        const u16* vr = (const u16*)&vreg;
#pragma unroll
        for (int jj = 0; jj < 8; jj++)
            Vt[0][(vcg * 8 + jj) * 72 + vt_t] = vr[jj];
    }

    bf16x8 qf[2];
    for (int g = 0; g < 2; g++) {
        union { uint4 u; bf16x8 f; } cv;
        cv.u = *(const uint4*)(q + base + (size_t)(n0 + g * 64 + wave * 16 + l16) * 32 + quad * 8);
        qf[g] = cv.f;
    }
    __syncthreads();

    bf16x8 ones;
    for (int i = 0; i < 8; i++) ones[i] = (__bf16)1.0f;

    // o_acc[g][0..1] = O columns ct*16+l16; o_acc[g][2] = denominator l
    f32x4 o_acc[2][3] = {};
    const int bn = (wave & 1) * 16 + l16;   // n & 31 (group-invariant)
    const int w2 = wave >> 1;

    // Bias register window as f32x4 chunks (= QK MFMA C-operand layout).
    // Rows: B = 2*kt - w2 + 1. g=1 uses rows (B,B+1) = X0/X1; g=0 uses
    // (B+2,B+3) = Y0/Y1. Chunk p2 covers cols cb + p2*16 + r.
    const int cb = quad * 4 + 31 - bn;
    f32x4 X0v[2], X1v[2], Y0v[2], Y1v[2];
#pragma unroll
    for (int p2 = 0; p2 < 2; p2++)
#pragma unroll
        for (int r = 0; r < 4; r++) {
            const int c37 = (cb + p2 * 16 + r) * 37;
            X0v[p2][r] = biasT[c37 + (1 - w2)];
            X1v[p2][r] = biasT[c37 + (2 - w2)];
            Y0v[p2][r] = biasT[c37 + (3 - w2)];
            Y1v[p2][r] = biasT[c37 + (4 - w2)];
        }

    for (int kt = 0; kt < 16; kt++) {
        const int cur = kt & 1;
        if (kt < 15) {   // prefetch next K/V tile into regs (in flight during compute)
            const int mn = (kt + 1) * 64;
            kreg = *(const uint4*)(k + base + (size_t)(mn + (tid >> 2)) * 32 + (tid & 3) * 8);
            vreg = *(const uint4*)(v + base + (size_t)(mn + vt_t) * 32 + vcg * 8);
        }

        bf16x8 kf[4];
#pragma unroll
        for (int j = 0; j < 4; j++)
            kf[j] = *(const bf16x8*)(Ks[cur] + (j * 16 + l16) * 40 + quad * 8);
        bf16x8 vf[2][2];                    // V frags: g-invariant, load once
#pragma unroll
        for (int kc = 0; kc < 2; kc++)
#pragma unroll
            for (int ct = 0; ct < 2; ct++)
                vf[kc][ct] = *(const bf16x8*)(Vt[cur] + (ct * 16 + l16) * 72 + kc * 32 + quad * 8);

#pragma unroll
        for (int g = 0; g < 2; g++) {
            // S^T tile with bias as C-operand: s4 = K^T(q*SC) + bias_l2e
            f32x4 s4[4];
#pragma unroll
            for (int j = 0; j < 4; j++) {
                const f32x4 Cb = g ? ((j >> 1) ? X1v[j & 1] : X0v[j & 1])
                                   : ((j >> 1) ? Y1v[j & 1] : Y0v[j & 1]);
                s4[j] = __builtin_amdgcn_mfma_f32_16x16x32_bf16(kf[j], qf[g], Cb, 0, 0, 0);
            }

            // softmax: exp2 directly (no fma), pack to bf16 words
            // Aw[j] = {P[16j+4q+0], P[16j+4q+1]}, Bw[j] = {+2, +3}
            u32 Aw[4], Bw[4];
#pragma unroll
            for (int j = 0; j < 4; j++) {
                u16 pk[4];
#pragma unroll
                for (int r = 0; r < 4; r++) {
                    const float pv = __builtin_amdgcn_exp2f(s4[j][r]);
                    union { __bf16 b; u16 u; } cv; cv.b = (__bf16)pv;
                    pk[r] = cv.u;
                }
                Aw[j] = ((u32)pk[1] << 16) | pk[0];
                Bw[j] = ((u32)pk[3] << 16) | pk[2];
            }

            // T12 redistribution: pa[kc] via 2x permlane32_swap + 2x permlane16_swap
#pragma unroll
            for (int kc = 0; kc < 2; kc++) {
                u32x2 ra = __builtin_amdgcn_permlane32_swap(Aw[2 * kc], Aw[2 * kc + 1], false, false);
                u32x2 wa = __builtin_amdgcn_permlane16_swap(ra.x, ra.y, false, false); // w0, w2
                u32x2 rb = __builtin_amdgcn_permlane32_swap(Bw[2 * kc], Bw[2 * kc + 1], false, false);
                u32x2 wb = __builtin_amdgcn_permlane16_swap(rb.x, rb.y, false, false); // w1, w3
                union { u32 w[4]; bf16x8 f; } pa;
                pa.w[0] = wa.x; pa.w[1] = wb.x; pa.w[2] = wa.y; pa.w[3] = wb.y;
#pragma unroll
                for (int ct = 0; ct < 2; ct++)
                    o_acc[g][ct] = __builtin_amdgcn_mfma_f32_16x16x32_bf16(pa.f, vf[kc][ct], o_acc[g][ct], 0, 0, 0);
                o_acc[g][2] = __builtin_amdgcn_mfma_f32_16x16x32_bf16(pa.f, ones, o_acc[g][2], 0, 0, 0);
            }
        }

        if (kt < 15) {
            // rotate bias window: X <- Y, load rows (B+4, B+5) into Y
#pragma unroll
            for (int p2 = 0; p2 < 2; p2++) { X0v[p2] = Y0v[p2]; X1v[p2] = Y1v[p2]; }
            const int nr = 2 * kt - w2 + 5;
#pragma unroll
            for (int p2 = 0; p2 < 2; p2++)
#pragma unroll
                for (int r = 0; r < 4; r++) {
                    const int c37 = (cb + p2 * 16 + r) * 37;
                    Y0v[p2][r] = biasT[c37 + nr];
                    Y1v[p2][r] = biasT[c37 + nr + 1];
                }
            // write prefetched K/V tile to back buffer (V transposed on the fly)
            *(uint4*)(Ks[cur ^ 1] + (tid >> 2) * 40 + (tid & 3) * 8) = kreg;
            const u16* vr = (const u16*)&vreg;
#pragma unroll
            for (int jj = 0; jj < 8; jj++)
                Vt[cur ^ 1][(vcg * 8 + jj) * 72 + vt_t] = vr[jj];
        }
        __syncthreads();
    }

    for (int g = 0; g < 2; g++)
        for (int r = 0; r < 4; r++) {
            const float inv = __builtin_amdgcn_rcpf(o_acc[g][2][r]);
            const int n = n0 + g * 64 + wave * 16 + quad * 4 + r;
            u16* orow = o + ((size_t)b * 1024 + n) * 512 + h * 32;
            orow[l16]      = f2bf(o_acc[g][0][r] * inv);
            orow[16 + l16] = f2bf(o_acc[g][1][r] * inv);
        }
}

extern "C" void kernel_launch(void* const* d_in, const int* in_sizes, int n_in,
                              void* d_out, int out_size, void* d_ws, size_t ws_size,
                              hipStream_t stream) {
    const void* x      = d_in[0];  // (8192,512)
    const void* qkv_w  = d_in[1];  // (1536,512)
    const void* qkv_b  = d_in[2];  // (1536)
    const void* rpb    = d_in[3];  // (16,63,63)
    const void* proj_w = d_in[4];  // (512,512)
    const void* proj_b = d_in[5];  // (512)

    // ws layout (u16 units). q lives in d_out (consumed by attn before the
    // proj GEMM overwrites d_out). r17: xbf deleted (GEMM1 reads raw x).
    u16* ws    = (u16*)d_ws;
    u16* kb    = ws;                   // [b][h][t][c]  8 MiB
    u16* vb    = ws + 4194304;         // [b][h][t][c]  8 MiB
    u16* ao    = ws + 8388608;         // (8192,512)    8 MiB
    u16* qwbf  = ws + 12582912;        // 1.5 MiB
    u16* pwbf  = ws + 13369344;        // 0.5 MiB
    u16* qbbf  = ws + 13631488;
    u16* pbbf  = ws + 13633024;
    float* rpl2e = (float*)(ws + 13633536);  // 254 KiB
    u16* qb    = (u16*)d_out;          // [b][h][t][c]  8 MiB

    convert_inputs<<<256, 256, 0, stream>>>(x, qkv_w, qkv_b, proj_w, proj_b, rpb,
                                            qwbf, qbbf, pwbf, pbbf, rpl2e);

    // QKV GEMM, TRANSPOSED: rows = channels (A = qkv_w), cols = tokens
    // (W-arg = RAW x, dual-dtype staging). q pre-scaled by SC.
    dim3 g1(8192 / 128, 1536 / 128);
    gemm_bt<1, 128><<<g1, 256, 0, stream>>>(qwbf, x, qbbf, nullptr, qb, kb, vb, x, 8192, 512);

    // attention: XCD-swizzled grid (x=h fixes XCD class per (b,h)), TQ=128
    dim3 g2(16, 8, 8);
    attn<<<g2, 256, 0, stream>>>(qb, kb, vb, rpl2e, ao);

    dim3 g3(512 / 128, 8192 / 64);
    gemm_bt<0, 64><<<g3, 256, 0, stream>>>(ao, pwbf, pbbf, d_out, nullptr, nullptr, nullptr, x, 512, 512);
}

// Round 8
// 146.512 us; speedup vs baseline: 1.0336x; 1.0336x over previous
//
#include <hip/hip_runtime.h>

typedef __bf16 bf16x8 __attribute__((ext_vector_type(8)));
typedef float f32x4 __attribute__((ext_vector_type(4)));
typedef unsigned int u32x2 __attribute__((ext_vector_type(2)));
typedef unsigned short u16;
typedef unsigned int u32;

__device__ __forceinline__ float bf2f(u16 v) {
    union { unsigned u; float f; } x; x.u = ((unsigned)v) << 16; return x.f;
}
__device__ __forceinline__ u16 f2bf(float f) {
    union { float f; unsigned u; } x; x.f = f;
    unsigned r = x.u + 0x7fffu + ((x.u >> 16) & 1u);
    return (u16)(r >> 16);
}

// Runtime dtype probe (HW-verified r4): f32 buffer -> low u16 of each word is
// mantissa bits -> bf16-exponent ~uniform (~44% >= 0x90); bf16 buffer -> 0 hits.
__device__ __forceinline__ bool probe_is_f32(const void* xp) {
    const unsigned* p = (const unsigned*)xp;
    int hits = 0;
#pragma unroll
    for (int i = 0; i < 32; i++) {
        const unsigned e = (p[i] >> 7) & 0xffu;
        hits += (e >= 0x90u) ? 1 : 0;
    }
    return hits > 3;
}

__device__ __forceinline__ float ld1(const void* p, size_t i, bool isf32) {
    return isf32 ? ((const float*)p)[i] : bf2f(((const u16*)p)[i]);
}

// Async global->LDS DMA, 16B/lane; LDS dest = wave-uniform base + lane*16.
__device__ __forceinline__ void gl2lds16(const void* g, void* l) {
    __builtin_amdgcn_global_load_lds(
        (const __attribute__((address_space(1))) u32*)g,
        (__attribute__((address_space(3))) u32*)l, 16, 0, 0);
}

// One-shot input normalization: everything -> bf16, rpb -> f32 * log2(e).
// (r18: x-pass RESTORED -- r17's raw-x reg-staging in GEMM1 regressed;
// DMA-from-bf16 is the proven path, the convert copy pays for itself.)
__global__ __launch_bounds__(256)
void convert_inputs(const void* __restrict__ x, const void* __restrict__ qw,
                    const void* __restrict__ qb, const void* __restrict__ pw,
                    const void* __restrict__ pb, const void* __restrict__ rp,
                    u16* __restrict__ xbf, u16* __restrict__ qwbf,
                    u16* __restrict__ qbbf, u16* __restrict__ pwbf,
                    u16* __restrict__ pbbf, float* __restrict__ rpl2e)
{
    const bool isf32 = probe_is_f32(x);
    const int gid = blockIdx.x * 256 + threadIdx.x;
    const int gsz = gridDim.x * 256;

    struct Seg { const void* s; u16* d; int n; };
    const Seg segs[5] = {{x, xbf, 4194304}, {qw, qwbf, 786432}, {pw, pwbf, 262144},
                         {qb, qbbf, 1536}, {pb, pbbf, 512}};
    for (int t = 0; t < 5; t++) {
        const int n4 = segs[t].n >> 2;
        if (isf32) {
            const f32x4* s = (const f32x4*)segs[t].s;
            for (int i = gid; i < n4; i += gsz) {
                f32x4 v = s[i];
                ushort4 o;
                o.x = f2bf(v[0]); o.y = f2bf(v[1]); o.z = f2bf(v[2]); o.w = f2bf(v[3]);
                *(ushort4*)(segs[t].d + i * 4) = o;
            }
        } else {
            const ushort4* s = (const ushort4*)segs[t].s;
            for (int i = gid; i < n4; i += gsz) *(ushort4*)(segs[t].d + i * 4) = s[i];
        }
    }
    for (int i = gid; i < 63504; i += gsz)
        rpl2e[i] = ld1(rp, i, isf32) * 1.4426950408889634f;
}

// GEMM D = A(MxK) @ W(NoutxK)^T + bias, pure bf16, fp32 accum. BMx128 tile.
// K-loop unrolled x2 with TWO independent BK=32 LDS buffers per operand.
// MODE 0: bias[col]; dual-dtype row-major store to d_out (probe decides).
// MODE 1 (TRANSPOSED QKV): A = qkv_w (rows = channels), W-arg = x (rows =
//   tokens). D[ch][tok]. bias[row]. which = m0>>9 block-uniform.
//   q,k,v all -> [b][h][t][c] packed ushort4 (r16).
//   r18: q output PRE-SCALED by SC = d^-0.5*log2e (folded into the bias fma)
//   so attn's softmax needs no fma before exp2.
template<int MODE, int BM>
__global__ __launch_bounds__(256, MODE == 1 ? 3 : 4)
void gemm_bt(const u16* __restrict__ A, const u16* __restrict__ W,
             const u16* __restrict__ bias, void* __restrict__ out,
             u16* __restrict__ q_out, u16* __restrict__ k_out, u16* __restrict__ v_out,
             const void* __restrict__ probe, int Nout, int K)
{
    __shared__ __align__(16) u16 As[2][BM * 32];
    __shared__ __align__(16) u16 Ws[2][128 * 32];
    constexpr int RW = BM / 32;            // A-frags per wave

    const int tid  = threadIdx.x;
    const int lane = tid & 63;
    const int wave = tid >> 6;
    const int quad = lane >> 4;
    const int l16  = lane & 15;
    const int m0 = blockIdx.y * BM;
    const int n0 = blockIdx.x * 128;
    const int wm = (wave >> 1) * (BM / 2);
    const int wn = (wave & 1) * 64;

    f32x4 acc[RW][4] = {};

    for (int k0 = 0; k0 < K; k0 += 64) {
        __syncthreads();
        for (int u = 0; u < 2; u++) {
            {
                const u16* g = A + (size_t)(m0 + wave * 16 + (lane >> 2)) * K
                                 + k0 + u * 32 + (lane & 3) * 8;
                u16* l = As[u] + wave * 16 * 32;
                for (int p = 0; p < BM / 64; p++) gl2lds16(g + (size_t)p * 64 * K, l + p * 64 * 32);
            }
            {
                const u16* g = W + (size_t)(n0 + wave * 16 + (lane >> 2)) * K
                                 + k0 + u * 32 + (lane & 3) * 8;
                u16* l = Ws[u] + wave * 16 * 32;
                for (int p = 0; p < 2; p++) gl2lds16(g + (size_t)p * 64 * K, l + p * 64 * 32);
            }
        }
        __syncthreads();

        for (int u = 0; u < 2; u++) {
            bf16x8 af[RW], wf[4];
            for (int i = 0; i < RW; i++)
                af[i] = *(const bf16x8*)(As[u] + (wm + i * 16 + l16) * 32 + quad * 8);
            for (int j = 0; j < 4; j++)
                wf[j] = *(const bf16x8*)(Ws[u] + (wn + j * 16 + l16) * 32 + quad * 8);
            for (int i = 0; i < RW; i++)
                for (int j = 0; j < 4; j++)
                    acc[i][j] = __builtin_amdgcn_mfma_f32_16x16x32_bf16(af[i], wf[j], acc[i][j], 0, 0, 0);
        }
    }

    // D layout per 16x16 tile: row = quad*4 + r, col = l16
    if (MODE == 0) {
        const bool isf32 = probe_is_f32(probe);
        for (int j = 0; j < 4; j++) {
            const int col = n0 + wn + j * 16 + l16;
            const float bv = bf2f(bias[col]);
            for (int i = 0; i < RW; i++) {
                const int rbase = m0 + wm + i * 16 + quad * 4;
                for (int r = 0; r < 4; r++) {
                    const float val = acc[i][j][r] + bv;
                    if (isf32) ((float*)out)[(size_t)(rbase + r) * Nout + col] = val;
                    else       ((u16*)out)[(size_t)(rbase + r) * Nout + col]  = f2bf(val);
                }
            }
        }
    } else {
        const int which = m0 >> 9;       // block-uniform (m0 128-aligned)
        u16* dst = which == 0 ? q_out : (which == 1 ? k_out : v_out);
        // q pre-scale: SC folded into the bias fma (single bf16 rounding).
        const float qsc = (which == 0) ? 0.25503485724582146f : 1.0f;
        float bv[RW][4];
        for (int i = 0; i < RW; i++) {
            const int row4 = m0 + wm + i * 16 + quad * 4;
            for (int r = 0; r < 4; r++) bv[i][r] = bf2f(bias[row4 + r]) * qsc;
        }
        for (int j = 0; j < 4; j++) {
            const int tok = n0 + wn + j * 16 + l16;
            const int bi = tok >> 10, t = tok & 1023;
            for (int i = 0; i < RW; i++) {
                ushort4 pk;
                pk.x = f2bf(acc[i][j][0] * qsc + bv[i][0]);
                pk.y = f2bf(acc[i][j][1] * qsc + bv[i][1]);
                pk.z = f2bf(acc[i][j][2] * qsc + bv[i][2]);
                pk.w = f2bf(acc[i][j][3] * qsc + bv[i][3]);
                const int row4 = m0 + wm + i * 16 + quad * 4;
                const int h = (row4 >> 5) & 15;
                const int c = row4 & 31;
                *(ushort4*)(dst + ((size_t)(bi * 16 + h) * 1024 + t) * 32 + c) = pk;
            }
        }
    }
}

// Flash attention, S^T formulation, offset-free softmax, MFMA denominator,
// T12 in-register P transpose (r14), V transposed during staging (r16),
// softmax fold (r18: q pre-scaled, bias as QK MFMA C-operand, softmax =
// bare exp2). XCD-SWIZZLED GRID (r10): grid (16,8,8) x=h,y=qt,z=b.
//
// Ledger: r11 K/V-from-global regressed; r12 setprio null; r13 bias
// reg-window neutral; r14 T12 permlane WIN; r15 TQ=64 null; r16 V-
// transpose-in-staging neutral; r17 raw-x reg-staging REGRESSED (reverted
// here; softmax fold kept and isolated this round).
__global__ __launch_bounds__(256, 4)
void attn(const u16* __restrict__ q, const u16* __restrict__ k,
          const u16* __restrict__ v, const float* __restrict__ rpl2e,
          u16* __restrict__ o)
{
    __shared__ __align__(16) u16 Ks[2][64 * 40];
    __shared__ __align__(16) u16 Vt[2][32 * 72];
    __shared__ float biasT[63 * 37];   // [col][row], 35 rows + 2 pad

    const int tid  = threadIdx.x;
    const int lane = tid & 63;
    const int wave = tid >> 6;
    const int quad = lane >> 4;
    const int l16  = lane & 15;

    const int h  = blockIdx.x;   // 16 heads (fastest -> fixes XCD class)
    const int qt = blockIdx.y;   // 8 q-tiles of 128
    const int b  = blockIdx.z;
    const int n0 = qt * 128;
    const size_t base = ((size_t)(b * 16 + h)) * 32768;  // q,k,v all [t][c]

    // ---- prologue: bias region (transposed), kt=0 K/V, Q frags ----
    {
        const int row0 = 28 - 4 * qt;
        for (int idx = tid; idx < 2205; idx += 256) {
            const int rr = idx / 63, cc = idx % 63;
            biasT[cc * 37 + rr] =
                rpl2e[(size_t)h * 3969 + (size_t)(row0 + rr) * 63 + cc];
        }
    }
    const int vt_t = lane;        // token within kv-tile
    const int vcg  = wave;        // c-group: c = vcg*8 .. +7
    uint4 kreg = *(const uint4*)(k + base + (size_t)(tid >> 2) * 32 + (tid & 3) * 8);
    uint4 vreg = *(const uint4*)(v + base + (size_t)vt_t * 32 + vcg * 8);
    *(uint4*)(Ks[0] + (tid >> 2) * 40 + (tid & 3) * 8) = kreg;
    {
        const u16* vr = (const u16*)&vreg;
#pragma unroll
        for (int jj = 0; jj < 8; jj++)
            Vt[0][(vcg * 8 + jj) * 72 + vt_t] = vr[jj];
    }

    bf16x8 qf[2];
    for (int g = 0; g < 2; g++) {
        union { uint4 u; bf16x8 f; } cv;
        cv.u = *(const uint4*)(q + base + (size_t)(n0 + g * 64 + wave * 16 + l16) * 32 + quad * 8);
        qf[g] = cv.f;
    }
    __syncthreads();

    bf16x8 ones;
    for (int i = 0; i < 8; i++) ones[i] = (__bf16)1.0f;

    // o_acc[g][0..1] = O columns ct*16+l16; o_acc[g][2] = denominator l
    f32x4 o_acc[2][3] = {};
    const int bn = (wave & 1) * 16 + l16;   // n & 31 (group-invariant)
    const int w2 = wave >> 1;

    // Bias register window as f32x4 chunks (= QK MFMA C-operand layout).
    // Rows: B = 2*kt - w2 + 1. g=1 uses rows (B,B+1) = X0/X1; g=0 uses
    // (B+2,B+3) = Y0/Y1. Chunk p2 covers cols cb + p2*16 + r.
    const int cb = quad * 4 + 31 - bn;
    f32x4 X0v[2], X1v[2], Y0v[2], Y1v[2];
#pragma unroll
    for (int p2 = 0; p2 < 2; p2++)
#pragma unroll
        for (int r = 0; r < 4; r++) {
            const int c37 = (cb + p2 * 16 + r) * 37;
            X0v[p2][r] = biasT[c37 + (1 - w2)];
            X1v[p2][r] = biasT[c37 + (2 - w2)];
            Y0v[p2][r] = biasT[c37 + (3 - w2)];
            Y1v[p2][r] = biasT[c37 + (4 - w2)];
        }

    for (int kt = 0; kt < 16; kt++) {
        const int cur = kt & 1;
        if (kt < 15) {   // prefetch next K/V tile into regs (in flight during compute)
            const int mn = (kt + 1) * 64;
            kreg = *(const uint4*)(k + base + (size_t)(mn + (tid >> 2)) * 32 + (tid & 3) * 8);
            vreg = *(const uint4*)(v + base + (size_t)(mn + vt_t) * 32 + vcg * 8);
        }

        bf16x8 kf[4];
#pragma unroll
        for (int j = 0; j < 4; j++)
            kf[j] = *(const bf16x8*)(Ks[cur] + (j * 16 + l16) * 40 + quad * 8);
        bf16x8 vf[2][2];                    // V frags: g-invariant, load once
#pragma unroll
        for (int kc = 0; kc < 2; kc++)
#pragma unroll
            for (int ct = 0; ct < 2; ct++)
                vf[kc][ct] = *(const bf16x8*)(Vt[cur] + (ct * 16 + l16) * 72 + kc * 32 + quad * 8);

#pragma unroll
        for (int g = 0; g < 2; g++) {
            // S^T tile with bias as C-operand: s4 = K^T(q*SC) + bias_l2e
            f32x4 s4[4];
#pragma unroll
            for (int j = 0; j < 4; j++) {
                const f32x4 Cb = g ? ((j >> 1) ? X1v[j & 1] : X0v[j & 1])
                                   : ((j >> 1) ? Y1v[j & 1] : Y0v[j & 1]);
                s4[j] = __builtin_amdgcn_mfma_f32_16x16x32_bf16(kf[j], qf[g], Cb, 0, 0, 0);
            }

            // softmax: exp2 directly (no fma), pack to bf16 words
            // Aw[j] = {P[16j+4q+0], P[16j+4q+1]}, Bw[j] = {+2, +3}
            u32 Aw[4], Bw[4];
#pragma unroll
            for (int j = 0; j < 4; j++) {
                u16 pk[4];
#pragma unroll
                for (int r = 0; r < 4; r++) {
                    const float pv = __builtin_amdgcn_exp2f(s4[j][r]);
                    union { __bf16 b; u16 u; } cv; cv.b = (__bf16)pv;
                    pk[r] = cv.u;
                }
                Aw[j] = ((u32)pk[1] << 16) | pk[0];
                Bw[j] = ((u32)pk[3] << 16) | pk[2];
            }

            // T12 redistribution: pa[kc] via 2x permlane32_swap + 2x permlane16_swap
#pragma unroll
            for (int kc = 0; kc < 2; kc++) {
                u32x2 ra = __builtin_amdgcn_permlane32_swap(Aw[2 * kc], Aw[2 * kc + 1], false, false);
                u32x2 wa = __builtin_amdgcn_permlane16_swap(ra.x, ra.y, false, false); // w0, w2
                u32x2 rb = __builtin_amdgcn_permlane32_swap(Bw[2 * kc], Bw[2 * kc + 1], false, false);
                u32x2 wb = __builtin_amdgcn_permlane16_swap(rb.x, rb.y, false, false); // w1, w3
                union { u32 w[4]; bf16x8 f; } pa;
                pa.w[0] = wa.x; pa.w[1] = wb.x; pa.w[2] = wa.y; pa.w[3] = wb.y;
#pragma unroll
                for (int ct = 0; ct < 2; ct++)
                    o_acc[g][ct] = __builtin_amdgcn_mfma_f32_16x16x32_bf16(pa.f, vf[kc][ct], o_acc[g][ct], 0, 0, 0);
                o_acc[g][2] = __builtin_amdgcn_mfma_f32_16x16x32_bf16(pa.f, ones, o_acc[g][2], 0, 0, 0);
            }
        }

        if (kt < 15) {
            // rotate bias window: X <- Y, load rows (B+4, B+5) into Y
#pragma unroll
            for (int p2 = 0; p2 < 2; p2++) { X0v[p2] = Y0v[p2]; X1v[p2] = Y1v[p2]; }
            const int nr = 2 * kt - w2 + 5;
#pragma unroll
            for (int p2 = 0; p2 < 2; p2++)
#pragma unroll
                for (int r = 0; r < 4; r++) {
                    const int c37 = (cb + p2 * 16 + r) * 37;
                    Y0v[p2][r] = biasT[c37 + nr];
                    Y1v[p2][r] = biasT[c37 + nr + 1];
                }
            // write prefetched K/V tile to back buffer (V transposed on the fly)
            *(uint4*)(Ks[cur ^ 1] + (tid >> 2) * 40 + (tid & 3) * 8) = kreg;
            const u16* vr = (const u16*)&vreg;
#pragma unroll
            for (int jj = 0; jj < 8; jj++)
                Vt[cur ^ 1][(vcg * 8 + jj) * 72 + vt_t] = vr[jj];
        }
        __syncthreads();
    }

    for (int g = 0; g < 2; g++)
        for (int r = 0; r < 4; r++) {
            const float inv = __builtin_amdgcn_rcpf(o_acc[g][2][r]);
            const int n = n0 + g * 64 + wave * 16 + quad * 4 + r;
            u16* orow = o + ((size_t)b * 1024 + n) * 512 + h * 32;
            orow[l16]      = f2bf(o_acc[g][0][r] * inv);
            orow[16 + l16] = f2bf(o_acc[g][1][r] * inv);
        }
}

extern "C" void kernel_launch(void* const* d_in, const int* in_sizes, int n_in,
                              void* d_out, int out_size, void* d_ws, size_t ws_size,
                              hipStream_t stream) {
    const void* x      = d_in[0];  // (8192,512)
    const void* qkv_w  = d_in[1];  // (1536,512)
    const void* qkv_b  = d_in[2];  // (1536)
    const void* rpb    = d_in[3];  // (16,63,63)
    const void* proj_w = d_in[4];  // (512,512)
    const void* proj_b = d_in[5];  // (512)

    // ws layout (u16 units), ~26.3 MiB. xbf aliases ao (disjoint lifetimes).
    // q lives in d_out (consumed by attn before proj GEMM overwrites d_out).
    u16* ws    = (u16*)d_ws;
    u16* kb    = ws;                   // [b][h][t][c]  8 MiB
    u16* vb    = ws + 4194304;         // [b][h][t][c]  8 MiB
    u16* xbf   = ws + 8388608;         // (8192,512)    8 MiB (== ao)
    u16* ao    = xbf;
    u16* qwbf  = ws + 12582912;        // 1.5 MiB
    u16* pwbf  = ws + 13369344;        // 0.5 MiB
    u16* qbbf  = ws + 13631488;
    u16* pbbf  = ws + 13633024;
    float* rpl2e = (float*)(ws + 13633536);  // 254 KiB
    u16* qb    = (u16*)d_out;          // [b][h][t][c]  8 MiB

    convert_inputs<<<1024, 256, 0, stream>>>(x, qkv_w, qkv_b, proj_w, proj_b, rpb,
                                             xbf, qwbf, qbbf, pwbf, pbbf, rpl2e);

    // QKV GEMM, TRANSPOSED: rows = channels (A = qkv_w), cols = tokens
    // (W-arg = xbf, gl2lds16 DMA). q pre-scaled by SC.
    dim3 g1(8192 / 128, 1536 / 128);
    gemm_bt<1, 128><<<g1, 256, 0, stream>>>(qwbf, xbf, qbbf, nullptr, qb, kb, vb, x, 8192, 512);

    // attention: XCD-swizzled grid (x=h fixes XCD class per (b,h)), TQ=128
    dim3 g2(16, 8, 8);
    attn<<<g2, 256, 0, stream>>>(qb, kb, vb, rpl2e, ao);

    dim3 g3(512 / 128, 8192 / 64);
    gemm_bt<0, 64><<<g3, 256, 0, stream>>>(ao, pwbf, pbbf, d_out, nullptr, nullptr, nullptr, x, 512, 512);
}